// Round 1
// baseline (1375.679 us; speedup 1.0000x reference)
//
#include <hip/hip_runtime.h>

// ---------------------------------------------------------------------------
// Fused Swin window attention, one block per window, 512 threads = 8 waves,
// wave = one head, whole window (64 tokens).
// Key trick: for mfma 16x16x16, the C/D register layout equals the A/B-frag
// layout of the TRANSPOSED matrix -> q/k/vT/P transposes are pure in-register
// bf16 packs (no LDS round-trips, no shuffles). Projections (q,k,v,out) use
// 16x16x32 against LDS-staged x / global weights.
// LDS: xs[64][264]us + os[64][264]us = 67584 B -> 2 blocks/CU, 2 barriers.
// ---------------------------------------------------------------------------

typedef __attribute__((ext_vector_type(8))) short short8;
typedef __attribute__((ext_vector_type(4))) short short4v;
typedef __attribute__((ext_vector_type(4))) float f4;
typedef __attribute__((ext_vector_type(2))) unsigned int u2v;
typedef __attribute__((ext_vector_type(4))) unsigned int u4v;

#define MFMA32(a, b, c) __builtin_amdgcn_mfma_f32_16x16x32_bf16((a), (b), (c), 0, 0, 0)

#if defined(__has_builtin) && __has_builtin(__builtin_amdgcn_mfma_f32_16x16x16bf16_1k)
#define MFMA16(a, b, c) __builtin_amdgcn_mfma_f32_16x16x16bf16_1k((a), (b), (c), 0, 0, 0)
#else
__device__ __forceinline__ f4 mfma16_asm(short4v a, short4v b, f4 c) {
  f4 d;
  asm("v_mfma_f32_16x16x16_bf16 %0, %1, %2, %3" : "=v"(d) : "v"(a), "v"(b), "v"(c));
  return d;
}
#define MFMA16(a, b, c) mfma16_asm((a), (b), (c))
#endif

__device__ __forceinline__ unsigned int bpack2(float a, float b) {
  unsigned int ua = __float_as_uint(a); ua += 0x7fffu + ((ua >> 16) & 1u);
  unsigned int ub = __float_as_uint(b); ub += 0x7fffu + ((ub >> 16) & 1u);
  return (ua >> 16) | (ub & 0xffff0000u);
}
__device__ __forceinline__ short f2bs(float a) {
  unsigned int u = __float_as_uint(a); u += 0x7fffu + ((u >> 16) & 1u);
  return (short)(u >> 16);
}
__device__ __forceinline__ short4v pack4(f4 a) {
  u2v p = {bpack2(a[0], a[1]), bpack2(a[2], a[3])};
  return __builtin_bit_cast(short4v, p);
}
__device__ __forceinline__ f4 max4(f4 a, f4 b) {
  f4 r; r[0] = fmaxf(a[0], b[0]); r[1] = fmaxf(a[1], b[1]);
  r[2] = fmaxf(a[2], b[2]); r[3] = fmaxf(a[3], b[3]); return r;
}

// ws layout (bytes):
//   Wall  bf16 [768][256]  @ 0        (393216)  rows: 0-255 q, 256-511 k, 512-767 v
//   Wpb   bf16 [256][256]  @ 393216   (131072)
//   ball  f32  [768]       @ 524288   (3072)
//   biasPT f32 [8][4][4][64][4] @ 527360 (131072)  bias_rel in S^T frag order
#define WS_WALL 0
#define WS_WPB 393216
#define WS_BALL 524288
#define WS_BIAS 527360
#define WS_TOTAL 658432

__global__ void prep_kernel(const float* __restrict__ Wq, const float* __restrict__ Wkv,
                            const float* __restrict__ bq, const float* __restrict__ bkv,
                            const float* __restrict__ bt, const float* __restrict__ Wp,
                            short* __restrict__ Wall, short* __restrict__ Wpb,
                            float* __restrict__ ball, float* __restrict__ biasPT) {
  int i = blockIdx.x * 256 + threadIdx.x;
  if (i < 196608) {                       // qkv weights -> bf16 (row-major)
    float v = (i < 65536) ? Wq[i] : Wkv[i - 65536];
    Wall[i] = f2bs(v);
  } else if (i < 262144) {                // out-proj weights -> bf16
    int j = i - 196608;
    Wpb[j] = f2bs(Wp[j]);
  } else if (i < 262912) {                // fused qkv bias
    int j = i - 262144;
    ball[j] = (j < 256) ? bq[j] : bkv[j - 256];
  } else if (i < 295680) {                // relative-position bias, S^T fragment order
    int j = i - 262912;
    int r = j & 3, ln = (j >> 2) & 63, ntq = (j >> 8) & 3, mtk = (j >> 10) & 3, hh = j >> 12;
    int nq = ntq * 16 + (ln & 15);          // query index (column of S^T)
    int mk = mtk * 16 + (ln >> 4) * 4 + r;  // key index   (row of S^T)
    int yi = nq >> 3, xi = nq & 7, yj = mk >> 3, xj = mk & 7;
    int idx = (yi - yj + 7) * 15 + (xi - xj + 7);
    biasPT[j] = bt[idx * 8 + hh];
  }
}

// LDS (ushort units): xs [64][264] @0 ; os [64][264] @16896. 67584 bytes.
#define OS_US 16896
#define LDS_BYTES 67584

__global__ __launch_bounds__(512, 4) void fused_wattn(
    const float* __restrict__ x, const short* __restrict__ Wall,
    const short* __restrict__ Wpb, const float* __restrict__ ball,
    const float* __restrict__ bp, const float* __restrict__ biasPT,
    const float* __restrict__ mask, float* __restrict__ out) {
  extern __shared__ unsigned short lds[];
  unsigned short* xs = lds;
  unsigned short* os = lds + OS_US;
  const int b = blockIdx.x;
  const int tid = threadIdx.x;
  const int lane = tid & 63;
  const int h = tid >> 6;               // wave = head
  const int c = lane & 15, qd = lane >> 4;
  const f4 FZ = {0.f, 0.f, 0.f, 0.f};

  // ---- stage x (64x256 f32) -> bf16 LDS, stride 264 us ----
  {
    const int row = tid >> 3, col = (tid & 7) * 32;
    const float4* src = (const float4*)(x + ((size_t)b * 64 + row) * 256 + col);
    u4v* dst = (u4v*)&xs[row * 264 + col];
#pragma unroll
    for (int i = 0; i < 4; ++i) {
      float4 a0 = src[2 * i], a1 = src[2 * i + 1];
      u4v w = {bpack2(a0.x, a0.y), bpack2(a0.z, a0.w), bpack2(a1.x, a1.y), bpack2(a1.z, a1.w)};
      dst[i] = w;
    }
  }
  __syncthreads();  // sync0: xs ready

  const float scale = 0.17677669529663687f;  // 1/sqrt(32)
  short4v qf[4][2], kf[4][2], va[2][4];

  // ---- q,k: D[d][t] = W x^T (A = weight rows, B = x rows), K=32 streaming ----
#pragma unroll
  for (int g = 0; g < 2; ++g) {
    f4 acc[2][4];
#pragma unroll
    for (int mo = 0; mo < 2; ++mo)
#pragma unroll
      for (int nt = 0; nt < 4; ++nt) acc[mo][nt] = FZ;
    const short* w0 = Wall + ((g * 256 + h * 32 + c) * 256) + qd * 8;
#pragma unroll
    for (int ks = 0; ks < 8; ++ks) {
      short8 wf0 = *(const short8*)(w0 + ks * 32);
      short8 wf1 = *(const short8*)(w0 + 16 * 256 + ks * 32);
      short8 xf[4];
#pragma unroll
      for (int nt = 0; nt < 4; ++nt)
        xf[nt] = *(const short8*)&xs[(nt * 16 + c) * 264 + qd * 8 + ks * 32];
#pragma unroll
      for (int nt = 0; nt < 4; ++nt) {
        acc[0][nt] = MFMA32(wf0, xf[nt], acc[0][nt]);
        acc[1][nt] = MFMA32(wf1, xf[nt], acc[1][nt]);
      }
    }
    // pack: C-regs of D[d][t] tile == K=16 frag of q[t][d] (row=t, k=d)
#pragma unroll
    for (int mo = 0; mo < 2; ++mo) {
      const f4 bb = *(const f4*)(ball + g * 256 + h * 32 + mo * 16 + qd * 4);
#pragma unroll
      for (int nt = 0; nt < 4; ++nt) {
        f4 a = acc[mo][nt] + bb;
        if (g == 0) { a *= scale; qf[nt][mo] = pack4(a); }
        else kf[nt][mo] = pack4(a);
      }
    }
  }
  // ---- v: D[t][d] = x W^T (A = x rows, B = weight rows); pack -> vT frags ----
  {
    f4 acc[4][2];
#pragma unroll
    for (int mt = 0; mt < 4; ++mt)
#pragma unroll
      for (int nd = 0; nd < 2; ++nd) acc[mt][nd] = FZ;
    const short* w0 = Wall + ((512 + h * 32 + c) * 256) + qd * 8;
#pragma unroll
    for (int ks = 0; ks < 8; ++ks) {
      short8 wf0 = *(const short8*)(w0 + ks * 32);
      short8 wf1 = *(const short8*)(w0 + 16 * 256 + ks * 32);
      short8 xf[4];
#pragma unroll
      for (int mt = 0; mt < 4; ++mt)
        xf[mt] = *(const short8*)&xs[(mt * 16 + c) * 264 + qd * 8 + ks * 32];
#pragma unroll
      for (int mt = 0; mt < 4; ++mt) {
        acc[mt][0] = MFMA32(xf[mt], wf0, acc[mt][0]);
        acc[mt][1] = MFMA32(xf[mt], wf1, acc[mt][1]);
      }
    }
#pragma unroll
    for (int nd = 0; nd < 2; ++nd) {
      const float bv = ball[512 + h * 32 + nd * 16 + c];
      const f4 bv4 = {bv, bv, bv, bv};
#pragma unroll
      for (int mt = 0; mt < 4; ++mt) va[nd][mt] = pack4(acc[mt][nd] + bv4);  // vT[d][t] frag
    }
  }

  // ---- S^T = k q^T (K=16 x2), bias+mask as C-init; softmax; PV (K=16) ----
  const float* bias_h = biasPT + h * 4096;  // [mk][nq][lane][4]
  const float* maskw = mask + (size_t)(b & 1023) * 4096;
  f4 O[2][4];
#pragma unroll
  for (int ma = 0; ma < 2; ++ma)
#pragma unroll
    for (int nq = 0; nq < 4; ++nq) O[ma][nq] = FZ;

#pragma unroll
  for (int nq = 0; nq < 4; ++nq) {
    f4 z[4];
#pragma unroll
    for (int mk = 0; mk < 4; ++mk) {
      f4 init = *(const f4*)(bias_h + ((mk * 4 + nq) * 64 + lane) * 4);
      init += *(const f4*)(maskw + (nq * 16 + c) * 64 + mk * 16 + qd * 4);
      z[mk] = MFMA16(kf[mk][0], qf[nq][0], init);
      z[mk] = MFMA16(kf[mk][1], qf[nq][1], z[mk]);
    }
    // softmax over keys (rows of S^T): in-lane 16 + xor16 + xor32
    f4 m4 = max4(max4(z[0], z[1]), max4(z[2], z[3]));
    float mx = fmaxf(fmaxf(m4[0], m4[1]), fmaxf(m4[2], m4[3]));
    mx = fmaxf(mx, __shfl_xor(mx, 16));
    mx = fmaxf(mx, __shfl_xor(mx, 32));
    f4 s4 = FZ;
#pragma unroll
    for (int mk = 0; mk < 4; ++mk) {
      f4 e;
      e[0] = __expf(z[mk][0] - mx); e[1] = __expf(z[mk][1] - mx);
      e[2] = __expf(z[mk][2] - mx); e[3] = __expf(z[mk][3] - mx);
      z[mk] = e; s4 += e;
    }
    float sm = s4[0] + s4[1] + s4[2] + s4[3];
    sm += __shfl_xor(sm, 16);
    sm += __shfl_xor(sm, 32);
    const float ci = 1.0f / sm;
    // P pack: C-regs of S^T tile == K=16 frag of P[query][key]; PV immediately
#pragma unroll
    for (int mk = 0; mk < 4; ++mk) {
      short4v p = pack4(z[mk] * ci);
      O[0][nq] = MFMA16(va[0][mk], p, O[0][nq]);
      O[1][nq] = MFMA16(va[1][mk], p, O[1][nq]);
    }
  }

  // ---- write O^T into os[token][h*32+d] ----
#pragma unroll
  for (int nq = 0; nq < 4; ++nq) {
    const int t = nq * 16 + c;
#pragma unroll
    for (int ma = 0; ma < 2; ++ma) {
      f4 o = O[ma][nq];
      u2v pk = {bpack2(o[0], o[1]), bpack2(o[2], o[3])};
      *(u2v*)&os[t * 264 + h * 32 + ma * 16 + qd * 4] = pk;
    }
  }
  __syncthreads();  // sync1: os complete

  // ---- out-proj: D[oc][t] = Wp os^T, + bp, f4 stores ----
  {
    f4 acc[2][4];
#pragma unroll
    for (int mo = 0; mo < 2; ++mo)
#pragma unroll
      for (int nt = 0; nt < 4; ++nt) acc[mo][nt] = FZ;
    const short* w0 = Wpb + (h * 32 + c) * 256 + qd * 8;
#pragma unroll
    for (int ks = 0; ks < 8; ++ks) {
      short8 wf0 = *(const short8*)(w0 + ks * 32);
      short8 wf1 = *(const short8*)(w0 + 16 * 256 + ks * 32);
#pragma unroll
      for (int nt = 0; nt < 4; ++nt) {
        short8 bo = *(const short8*)&os[(nt * 16 + c) * 264 + qd * 8 + ks * 32];
        acc[0][nt] = MFMA32(wf0, bo, acc[0][nt]);
        acc[1][nt] = MFMA32(wf1, bo, acc[1][nt]);
      }
    }
#pragma unroll
    for (int mo = 0; mo < 2; ++mo) {
      const f4 bb = *(const f4*)(bp + h * 32 + mo * 16 + qd * 4);
#pragma unroll
      for (int nt = 0; nt < 4; ++nt) {
        f4 a = acc[mo][nt] + bb;
        *(f4*)(out + ((size_t)b * 64 + nt * 16 + c) * 256 + h * 32 + mo * 16 + qd * 4) = a;
      }
    }
  }
}

extern "C" void kernel_launch(void* const* d_in, const int* in_sizes, int n_in,
                              void* d_out, int out_size, void* d_ws, size_t ws_size,
                              hipStream_t stream) {
  const float* x = (const float*)d_in[0];
  const float* mask = (const float*)d_in[1];
  const float* Wq = (const float*)d_in[2];
  const float* bq = (const float*)d_in[3];
  const float* Wkv = (const float*)d_in[4];
  const float* bkv = (const float*)d_in[5];
  const float* bt = (const float*)d_in[6];
  const float* Wp = (const float*)d_in[7];
  const float* bp = (const float*)d_in[8];
  float* out = (float*)d_out;
  char* ws = (char*)d_ws;

  short* Wall = (short*)(ws + WS_WALL);
  short* Wpb = (short*)(ws + WS_WPB);
  float* ball = (float*)(ws + WS_BALL);
  float* biasPT = (float*)(ws + WS_BIAS);

  prep_kernel<<<1155, 256, 0, stream>>>(Wq, Wkv, bq, bkv, bt, Wp, Wall, Wpb, ball, biasPT);

  (void)hipFuncSetAttribute((const void*)fused_wattn,
                            hipFuncAttributeMaxDynamicSharedMemorySize, LDS_BYTES);
  fused_wattn<<<4096, 512, LDS_BYTES, stream>>>(x, Wall, Wpb, ball, bp, biasPT, mask, out);
}

// Round 2
// 733.249 us; speedup vs baseline: 1.8761x; 1.8761x over previous
//
#include <hip/hip_runtime.h>

// ---------------------------------------------------------------------------
// Fused Swin window attention, one block per window, 512 threads = 8 waves,
// wave = one head, whole window (64 tokens).
// Key trick: for mfma 16x16x16, the C/D register layout equals the A/B-frag
// layout of the TRANSPOSED matrix -> q/k/vT/P transposes are pure in-register
// bf16 packs (no LDS round-trips, no shuffles). Projections (q,k,v,out) use
// 16x16x32 against LDS-staged x / global weights.
// Round-2 fixes vs round-1 (which spilled ~1.2KB/thread -> 3.4GB scratch):
//   * O stored to LDS per-nq (accumulator live range 32 -> 8 regs)
//   * sched_barrier(0) per nq iteration + after v-pack stops unroll-driven
//     load/MFMA hoisting that inflated live ranges past the 128-VGPR cap.
// LDS: xs[64][264]us + os[64][264]us = 67584 B -> 2 blocks/CU, 2 barriers.
// ---------------------------------------------------------------------------

typedef __attribute__((ext_vector_type(8))) short short8;
typedef __attribute__((ext_vector_type(4))) short short4v;
typedef __attribute__((ext_vector_type(4))) float f4;
typedef __attribute__((ext_vector_type(2))) unsigned int u2v;
typedef __attribute__((ext_vector_type(4))) unsigned int u4v;

#define MFMA32(a, b, c) __builtin_amdgcn_mfma_f32_16x16x32_bf16((a), (b), (c), 0, 0, 0)

#if defined(__has_builtin) && __has_builtin(__builtin_amdgcn_mfma_f32_16x16x16bf16_1k)
#define MFMA16(a, b, c) __builtin_amdgcn_mfma_f32_16x16x16bf16_1k((a), (b), (c), 0, 0, 0)
#else
__device__ __forceinline__ f4 mfma16_asm(short4v a, short4v b, f4 c) {
  f4 d;
  asm("v_mfma_f32_16x16x16_bf16 %0, %1, %2, %3" : "=v"(d) : "v"(a), "v"(b), "v"(c));
  return d;
}
#define MFMA16(a, b, c) mfma16_asm((a), (b), (c))
#endif

__device__ __forceinline__ unsigned int bpack2(float a, float b) {
  unsigned int ua = __float_as_uint(a); ua += 0x7fffu + ((ua >> 16) & 1u);
  unsigned int ub = __float_as_uint(b); ub += 0x7fffu + ((ub >> 16) & 1u);
  return (ua >> 16) | (ub & 0xffff0000u);
}
__device__ __forceinline__ short f2bs(float a) {
  unsigned int u = __float_as_uint(a); u += 0x7fffu + ((u >> 16) & 1u);
  return (short)(u >> 16);
}
__device__ __forceinline__ short4v pack4(f4 a) {
  u2v p = {bpack2(a[0], a[1]), bpack2(a[2], a[3])};
  return __builtin_bit_cast(short4v, p);
}
__device__ __forceinline__ f4 max4(f4 a, f4 b) {
  f4 r; r[0] = fmaxf(a[0], b[0]); r[1] = fmaxf(a[1], b[1]);
  r[2] = fmaxf(a[2], b[2]); r[3] = fmaxf(a[3], b[3]); return r;
}

// ws layout (bytes):
//   Wall  bf16 [768][256]  @ 0        (393216)  rows: 0-255 q, 256-511 k, 512-767 v
//   Wpb   bf16 [256][256]  @ 393216   (131072)
//   ball  f32  [768]       @ 524288   (3072)
//   biasPT f32 [8][4][4][64][4] @ 527360 (131072)  bias_rel in S^T frag order
#define WS_WALL 0
#define WS_WPB 393216
#define WS_BALL 524288
#define WS_BIAS 527360
#define WS_TOTAL 658432

__global__ void prep_kernel(const float* __restrict__ Wq, const float* __restrict__ Wkv,
                            const float* __restrict__ bq, const float* __restrict__ bkv,
                            const float* __restrict__ bt, const float* __restrict__ Wp,
                            short* __restrict__ Wall, short* __restrict__ Wpb,
                            float* __restrict__ ball, float* __restrict__ biasPT) {
  int i = blockIdx.x * 256 + threadIdx.x;
  if (i < 196608) {                       // qkv weights -> bf16 (row-major)
    float v = (i < 65536) ? Wq[i] : Wkv[i - 65536];
    Wall[i] = f2bs(v);
  } else if (i < 262144) {                // out-proj weights -> bf16
    int j = i - 196608;
    Wpb[j] = f2bs(Wp[j]);
  } else if (i < 262912) {                // fused qkv bias
    int j = i - 262144;
    ball[j] = (j < 256) ? bq[j] : bkv[j - 256];
  } else if (i < 295680) {                // relative-position bias, S^T fragment order
    int j = i - 262912;
    int r = j & 3, ln = (j >> 2) & 63, ntq = (j >> 8) & 3, mtk = (j >> 10) & 3, hh = j >> 12;
    int nq = ntq * 16 + (ln & 15);          // query index (column of S^T)
    int mk = mtk * 16 + (ln >> 4) * 4 + r;  // key index   (row of S^T)
    int yi = nq >> 3, xi = nq & 7, yj = mk >> 3, xj = mk & 7;
    int idx = (yi - yj + 7) * 15 + (xi - xj + 7);
    biasPT[j] = bt[idx * 8 + hh];
  }
}

// LDS (ushort units): xs [64][264] @0 ; os [64][264] @16896. 67584 bytes.
#define OS_US 16896
#define LDS_BYTES 67584

__global__ __launch_bounds__(512, 4) void fused_wattn(
    const float* __restrict__ x, const short* __restrict__ Wall,
    const short* __restrict__ Wpb, const float* __restrict__ ball,
    const float* __restrict__ bp, const float* __restrict__ biasPT,
    const float* __restrict__ mask, float* __restrict__ out) {
  extern __shared__ unsigned short lds[];
  unsigned short* xs = lds;
  unsigned short* os = lds + OS_US;
  const int b = blockIdx.x;
  const int tid = threadIdx.x;
  const int lane = tid & 63;
  const int h = tid >> 6;               // wave = head
  const int c = lane & 15, qd = lane >> 4;
  const f4 FZ = {0.f, 0.f, 0.f, 0.f};

  // ---- stage x (64x256 f32) -> bf16 LDS, stride 264 us ----
  {
    const int row = tid >> 3, col = (tid & 7) * 32;
    const float4* src = (const float4*)(x + ((size_t)b * 64 + row) * 256 + col);
    u4v* dst = (u4v*)&xs[row * 264 + col];
#pragma unroll
    for (int i = 0; i < 4; ++i) {
      float4 a0 = src[2 * i], a1 = src[2 * i + 1];
      u4v w = {bpack2(a0.x, a0.y), bpack2(a0.z, a0.w), bpack2(a1.x, a1.y), bpack2(a1.z, a1.w)};
      dst[i] = w;
    }
  }
  __syncthreads();  // sync0: xs ready

  const float scale = 0.17677669529663687f;  // 1/sqrt(32)
  short4v qf[4][2], kf[4][2], va[2][4];

  // ---- q,k: D[d][t] = W x^T (A = weight rows, B = x rows), K=32 streaming ----
#pragma unroll
  for (int g = 0; g < 2; ++g) {
    f4 acc[2][4];
#pragma unroll
    for (int mo = 0; mo < 2; ++mo)
#pragma unroll
      for (int nt = 0; nt < 4; ++nt) acc[mo][nt] = FZ;
    const short* w0 = Wall + ((g * 256 + h * 32 + c) * 256) + qd * 8;
#pragma unroll
    for (int ks = 0; ks < 8; ++ks) {
      short8 wf0 = *(const short8*)(w0 + ks * 32);
      short8 wf1 = *(const short8*)(w0 + 16 * 256 + ks * 32);
      short8 xf[4];
#pragma unroll
      for (int nt = 0; nt < 4; ++nt)
        xf[nt] = *(const short8*)&xs[(nt * 16 + c) * 264 + qd * 8 + ks * 32];
#pragma unroll
      for (int nt = 0; nt < 4; ++nt) {
        acc[0][nt] = MFMA32(wf0, xf[nt], acc[0][nt]);
        acc[1][nt] = MFMA32(wf1, xf[nt], acc[1][nt]);
      }
    }
    // pack: C-regs of D[d][t] tile == K=16 frag of q[t][d] (row=t, k=d)
#pragma unroll
    for (int mo = 0; mo < 2; ++mo) {
      const f4 bb = *(const f4*)(ball + g * 256 + h * 32 + mo * 16 + qd * 4);
#pragma unroll
      for (int nt = 0; nt < 4; ++nt) {
        f4 a = acc[mo][nt] + bb;
        if (g == 0) { a *= scale; qf[nt][mo] = pack4(a); }
        else kf[nt][mo] = pack4(a);
      }
    }
    __builtin_amdgcn_sched_barrier(0);
  }
  // ---- v: D[t][d] = x W^T (A = x rows, B = weight rows); pack -> vT frags ----
  {
    f4 acc[4][2];
#pragma unroll
    for (int mt = 0; mt < 4; ++mt)
#pragma unroll
      for (int nd = 0; nd < 2; ++nd) acc[mt][nd] = FZ;
    const short* w0 = Wall + ((512 + h * 32 + c) * 256) + qd * 8;
#pragma unroll
    for (int ks = 0; ks < 8; ++ks) {
      short8 wf0 = *(const short8*)(w0 + ks * 32);
      short8 wf1 = *(const short8*)(w0 + 16 * 256 + ks * 32);
      short8 xf[4];
#pragma unroll
      for (int mt = 0; mt < 4; ++mt)
        xf[mt] = *(const short8*)&xs[(mt * 16 + c) * 264 + qd * 8 + ks * 32];
#pragma unroll
      for (int mt = 0; mt < 4; ++mt) {
        acc[mt][0] = MFMA32(xf[mt], wf0, acc[mt][0]);
        acc[mt][1] = MFMA32(xf[mt], wf1, acc[mt][1]);
      }
    }
#pragma unroll
    for (int nd = 0; nd < 2; ++nd) {
      const float bv = ball[512 + h * 32 + nd * 16 + c];
      const f4 bv4 = {bv, bv, bv, bv};
#pragma unroll
      for (int mt = 0; mt < 4; ++mt) va[nd][mt] = pack4(acc[mt][nd] + bv4);  // vT[d][t] frag
    }
    __builtin_amdgcn_sched_barrier(0);
  }

  // ---- S^T = k q^T (K=16 x2), bias+mask as C-init; softmax; PV (K=16) ----
  const float* bias_h = biasPT + h * 4096;  // [mk][nq][lane][4]
  const float* maskw = mask + (size_t)(b & 1023) * 4096;

#pragma unroll
  for (int nq = 0; nq < 4; ++nq) {
    f4 z[4];
#pragma unroll
    for (int mk = 0; mk < 4; ++mk) {
      f4 init = *(const f4*)(bias_h + ((mk * 4 + nq) * 64 + lane) * 4);
      init += *(const f4*)(maskw + (nq * 16 + c) * 64 + mk * 16 + qd * 4);
      z[mk] = MFMA16(kf[mk][0], qf[nq][0], init);
      z[mk] = MFMA16(kf[mk][1], qf[nq][1], z[mk]);
    }
    // softmax over keys (rows of S^T): in-lane 16 + xor16 + xor32
    f4 m4 = max4(max4(z[0], z[1]), max4(z[2], z[3]));
    float mx = fmaxf(fmaxf(m4[0], m4[1]), fmaxf(m4[2], m4[3]));
    mx = fmaxf(mx, __shfl_xor(mx, 16));
    mx = fmaxf(mx, __shfl_xor(mx, 32));
    f4 s4 = FZ;
#pragma unroll
    for (int mk = 0; mk < 4; ++mk) {
      f4 e;
      e[0] = __expf(z[mk][0] - mx); e[1] = __expf(z[mk][1] - mx);
      e[2] = __expf(z[mk][2] - mx); e[3] = __expf(z[mk][3] - mx);
      z[mk] = e; s4 += e;
    }
    float sm = s4[0] + s4[1] + s4[2] + s4[3];
    sm += __shfl_xor(sm, 16);
    sm += __shfl_xor(sm, 32);
    const float ci = 1.0f / sm;
    // P pack: C-regs of S^T tile == K=16 frag of P[query][key]; PV immediately
    f4 O0 = FZ, O1 = FZ;
#pragma unroll
    for (int mk = 0; mk < 4; ++mk) {
      short4v p = pack4(z[mk] * ci);
      O0 = MFMA16(va[0][mk], p, O0);
      O1 = MFMA16(va[1][mk], p, O1);
    }
    // ---- write O^T for this nq into os[token][h*32+d] (frees accs now) ----
    const int t = nq * 16 + c;
    u2v pk0 = {bpack2(O0[0], O0[1]), bpack2(O0[2], O0[3])};
    u2v pk1 = {bpack2(O1[0], O1[1]), bpack2(O1[2], O1[3])};
    *(u2v*)&os[t * 264 + h * 32 + qd * 4] = pk0;
    *(u2v*)&os[t * 264 + h * 32 + 16 + qd * 4] = pk1;
    __builtin_amdgcn_sched_barrier(0);
  }
  __syncthreads();  // sync1: os complete

  // ---- out-proj: D[oc][t] = Wp os^T, + bp, f4 stores ----
  {
    f4 acc[2][4];
#pragma unroll
    for (int mo = 0; mo < 2; ++mo)
#pragma unroll
      for (int nt = 0; nt < 4; ++nt) acc[mo][nt] = FZ;
    const short* w0 = Wpb + (h * 32 + c) * 256 + qd * 8;
#pragma unroll
    for (int ks = 0; ks < 8; ++ks) {
      short8 wf0 = *(const short8*)(w0 + ks * 32);
      short8 wf1 = *(const short8*)(w0 + 16 * 256 + ks * 32);
#pragma unroll
      for (int nt = 0; nt < 4; ++nt) {
        short8 bo = *(const short8*)&os[(nt * 16 + c) * 264 + qd * 8 + ks * 32];
        acc[0][nt] = MFMA32(wf0, bo, acc[0][nt]);
        acc[1][nt] = MFMA32(wf1, bo, acc[1][nt]);
      }
    }
#pragma unroll
    for (int mo = 0; mo < 2; ++mo) {
      const f4 bb = *(const f4*)(bp + h * 32 + mo * 16 + qd * 4);
#pragma unroll
      for (int nt = 0; nt < 4; ++nt) {
        f4 a = acc[mo][nt] + bb;
        *(f4*)(out + ((size_t)b * 64 + nt * 16 + c) * 256 + h * 32 + mo * 16 + qd * 4) = a;
      }
    }
  }
}

extern "C" void kernel_launch(void* const* d_in, const int* in_sizes, int n_in,
                              void* d_out, int out_size, void* d_ws, size_t ws_size,
                              hipStream_t stream) {
  const float* x = (const float*)d_in[0];
  const float* mask = (const float*)d_in[1];
  const float* Wq = (const float*)d_in[2];
  const float* bq = (const float*)d_in[3];
  const float* Wkv = (const float*)d_in[4];
  const float* bkv = (const float*)d_in[5];
  const float* bt = (const float*)d_in[6];
  const float* Wp = (const float*)d_in[7];
  const float* bp = (const float*)d_in[8];
  float* out = (float*)d_out;
  char* ws = (char*)d_ws;

  short* Wall = (short*)(ws + WS_WALL);
  short* Wpb = (short*)(ws + WS_WPB);
  float* ball = (float*)(ws + WS_BALL);
  float* biasPT = (float*)(ws + WS_BIAS);

  prep_kernel<<<1155, 256, 0, stream>>>(Wq, Wkv, bq, bkv, bt, Wp, Wall, Wpb, ball, biasPT);

  (void)hipFuncSetAttribute((const void*)fused_wattn,
                            hipFuncAttributeMaxDynamicSharedMemorySize, LDS_BYTES);
  fused_wattn<<<4096, 512, LDS_BYTES, stream>>>(x, Wall, Wpb, ball, bp, biasPT, mask, out);
}